// Round 16
// baseline (699.627 us; speedup 1.0000x reference)
//
#include <hip/hip_runtime.h>
#include <hip/hip_bf16.h>
#include <math.h>

#define BB 32
#define CC 64
#define C2 32
#define HH 32
#define WW 32
#define HW 1024
#define NTOT 3278
#define NPAD2 3328   // padded N (multiple of 128) for MFMA corr + fold
#define NT26 26      // NPAD2 / 128

typedef __bf16   bf16x8 __attribute__((ext_vector_type(8)));
typedef _Float16 half8  __attribute__((ext_vector_type(8)));
typedef float    f32x4  __attribute__((ext_vector_type(4)));

__device__ __constant__ int SC_SIZE[5] = {32, 28, 25, 22, 19};
__device__ __constant__ int SC_OFF[6]  = {0, 1024, 1808, 2433, 2917, 3278};

// ---------------- fused feature kernel: LDS-staged, x read once ----------------
#define XS_STR 65
#define WS_STR 132
__global__ void __launch_bounds__(256, 1) k_feats(
        const float* __restrict__ x,
        const float* __restrict__ wb, const float* __restrict__ bb, const float* __restrict__ ab,
        const float* __restrict__ wm, const float* __restrict__ bm, const float* __restrict__ am,
        const float* __restrict__ wa, const float* __restrict__ ba, const float* __restrict__ aa,
        _Float16* __restrict__ mft, _Float16* __restrict__ rft,
        __bf16* __restrict__ basef,
        float* __restrict__ mbss, float* __restrict__ rmss) {
    __shared__ float Xs[64 * XS_STR];     // [c][p]
    __shared__ float Wls[64 * WS_STR];    // [c][o]
    __shared__ float bsh[128];
    __shared__ float ash3[3];
    int tid = threadIdx.x;
    int g0 = blockIdx.x * 64;
    int b = g0 >> 10, p0 = g0 & 1023;

    const float* xb = x + (size_t)b * CC * HW + p0;
    for (int i = tid; i < 64 * 64; i += 256) {
        int c = i >> 6, p = i & 63;
        Xs[c * XS_STR + p] = xb[(size_t)c * HW + p];
    }
    for (int i = tid; i < 128 * 64; i += 256) {
        int o = i >> 6, c = i & 63;
        float w = (o < 32) ? wb[o * CC + c] : (o < 64) ? wm[(o - 32) * CC + c] : wa[(o - 64) * CC + c];
        Wls[c * WS_STR + o] = w;
    }
    if (tid < 128) bsh[tid] = (tid < 32) ? bb[tid] : (tid < 64) ? bm[tid - 32] : ba[tid - 64];
    if (tid == 128) ash3[0] = ab[0];
    if (tid == 129) ash3[1] = am[0];
    if (tid == 130) ash3[2] = aa[0];
    __syncthreads();

    int p = tid & 63, og = tid >> 6;
    int o0 = og * 32;
    float acc[32];
#pragma unroll
    for (int oi = 0; oi < 32; ++oi) acc[oi] = bsh[o0 + oi];
    for (int c = 0; c < 64; ++c) {
        float xv = Xs[c * XS_STR + p];
        const float* wr = &Wls[c * WS_STR + o0];
#pragma unroll
        for (int oi = 0; oi < 32; ++oi) acc[oi] += wr[oi] * xv;
    }
    int pp = p0 + p;
    if (og < 2) {
        float alpha = ash3[og], ss = 0.f;
        half8 hv[4];
#pragma unroll
        for (int oi = 0; oi < 32; ++oi) {
            float v = acc[oi] >= 0.f ? acc[oi] : alpha * acc[oi];
            ss += v * v;
            hv[oi >> 3][oi & 7] = (_Float16)v;
        }
        _Float16* d = (og == 0 ? mft : rft) + ((size_t)b * HW + pp) * 32;
#pragma unroll
        for (int q = 0; q < 4; ++q) *(half8*)&d[q * 8] = hv[q];
        if (og == 0) mbss[(size_t)b * HW + pp] = ss;
        else         rmss[(size_t)b * HW + pp] = ss;
    } else {
        float alpha = ash3[2];
        int ob = o0 - 64;
#pragma unroll
        for (int oi = 0; oi < 32; ++oi) {
            float v = acc[oi] >= 0.f ? acc[oi] : alpha * acc[oi];
            basef[((size_t)b * CC + ob + oi) * HW + pp] = (__bf16)v;
        }
    }
}

// ---------------- neighbor table ----------------
__global__ void k_nbr(int* __restrict__ nbr_pos) {
    int n = blockIdx.x * blockDim.x + threadIdx.x;
    if (n >= NTOT) return;
    int s = 0;
    while (s < 4 && n >= SC_OFF[s + 1]) ++s;
    int q = n - SC_OFF[s];
    int hs = SC_SIZE[s];
    int ny = q / hs, nx = q % hs;
    for (int dy = 0; dy < 3; ++dy)
        for (int dx = 0; dx < 3; ++dx) {
            int yy = ny + dy - 1, xx = nx + dx - 1;
            int pos = -1;
            if (yy >= 0 && yy < hs && xx >= 0 && xx < hs)
                pos = ((yy * HH) / hs) * WW + (xx * WW) / hs;
            nbr_pos[(dy * 3 + dx) * NTOT + n] = pos;
        }
}

// ---------------- per-(b,p) logit upper bound ----------------
__global__ void k_qnorm(const float* __restrict__ mbss, float* __restrict__ qub) {
    int t = blockIdx.x * blockDim.x + threadIdx.x;
    int b = t >> 10, p = t & 1023;
    int y = p >> 5, x = p & 31;
    float s = 0.f;
#pragma unroll
    for (int dy = 0; dy < 3; ++dy)
#pragma unroll
        for (int dx = 0; dx < 3; ++dx) {
            int yy = y + dy - 1, xx = x + dx - 1;
            if (yy >= 0 && yy < HH && xx >= 0 && xx < WW)
                s += mbss[(size_t)b * HW + yy * WW + xx];
        }
    qub[t] = 10.0f * sqrtf(s);
}

// ---------------- per-(b,n) filter norms ----------------
__global__ void k_norms(const float* __restrict__ rmss, const int* __restrict__ nbr_pos,
                        float* __restrict__ sinv) {
    int t = blockIdx.x * blockDim.x + threadIdx.x;
    if (t >= BB * NTOT) return;
    int b = t / NTOT, n = t % NTOT;
    float sum = 0.f;
#pragma unroll
    for (int kk = 0; kk < 9; ++kk) {
        int pos = nbr_pos[kk * NTOT + n];
        if (pos >= 0) sum += rmss[(size_t)b * HW + pos];
    }
    sinv[t] = 10.0f / fmaxf(sqrtf(sum), 1e-4f);
}

// ---------------- V gather (vectorized): thread -> 8 consecutive n ----------------
__global__ void k_vgather(const __bf16* __restrict__ basef, const int* __restrict__ nbr_pos,
                          __bf16* __restrict__ Vb, int b0) {
    int t = blockIdx.x * 256 + threadIdx.x;
    int cb = blockIdx.y;
    int m = t / (NPAD2 / 8), nq = t % (NPAD2 / 8);
    int c = m / 9, kk = m - c * 9;
    const __bf16* bfp = basef + ((size_t)(b0 + cb) * CC + c) * HW;
    const int* nb = &nbr_pos[kk * NTOT];
    int n0 = nq * 8;
    bf16x8 v8;
#pragma unroll
    for (int u = 0; u < 8; ++u) {
        int n = n0 + u;
        __bf16 v = (__bf16)0.f;
        if (n < NTOT) {
            int pos = nb[n];
            if (pos >= 0) v = bfp[pos];
        }
        v8[u] = v;
    }
    *(bf16x8*)&Vb[((size_t)cb * 576 + m) * NPAD2 + n0] = v8;
}

// ---------------- correlation GEMM: fp16, 64x128 tile, reg prefetch, wave-local store ----------------
__global__ void k_corr_mfma(const _Float16* __restrict__ mft, const _Float16* __restrict__ rft,
                            const int* __restrict__ nbr_pos,
                            const float* __restrict__ sinv, const float* __restrict__ qub,
                            __bf16* __restrict__ tbuf, float* __restrict__ partS, int b0) {
    int ptile = blockIdx.x;   // 16 tiles of 64 p
    int ntile = blockIdx.y;   // 26 tiles of 128 n
    int cb    = blockIdx.z;
    int tid  = threadIdx.x;
    int lane = tid & 63, wave = tid >> 6;
    int row16 = lane & 15, quad = lane >> 4;
    int p0 = ptile * 64, n0 = ntile * 128;

    __shared__ _Float16 Ah[64 * 40];
    __shared__ _Float16 Bh[128 * 40];
    __shared__ int   nbrs[9][128];
    __shared__ float sMub[64];
    __shared__ float redS[4][64];
    __shared__ __bf16 Tls[4][16 * 40];   // per-wave transpose slab (16 rows x 32 cols)

    if (tid < 64) sMub[tid] = qub[(size_t)(b0 + cb) * HW + p0 + tid];
    for (int i = tid; i < 9 * 128; i += 256) {
        int kk = i >> 7, j = i & 127;
        int n = n0 + j;
        nbrs[kk][j] = (n < NTOT) ? nbr_pos[kk * NTOT + n] : -1;
    }

    const _Float16* mh = mft + (size_t)(b0 + cb) * HW * 32;
    const _Float16* rh = rft + (size_t)(b0 + cb) * HW * 32;

    f32x4 acc[4][2];
#pragma unroll
    for (int i = 0; i < 4; ++i)
#pragma unroll
        for (int j = 0; j < 2; ++j) acc[i][j] = (f32x4){0.f, 0.f, 0.f, 0.f};

    half8 zero8;
#pragma unroll
    for (int u = 0; u < 8; ++u) zero8[u] = (_Float16)0.f;

    __syncthreads();   // nbrs, sMub ready

    half8 pA, pB[2];
    int ap = tid >> 2, ac = (tid & 3) * 8;   // A task: 64 p x 4 c-octs = 256 tasks
    int pg = p0 + ap, ay = pg >> 5, ax = pg & 31;
    auto gatherA = [&](int kk, half8* dst) {
        int py = ay + kk / 3 - 1, px = ax + (kk % 3) - 1;
        bool ok = (py >= 0 && py < HH && px >= 0 && px < WW);
        *dst = ok ? *(const half8*)(mh + (size_t)(py * WW + px) * 32 + ac) : zero8;
    };
    auto gatherB = [&](int kk, half8* dst) {
#pragma unroll
        for (int it = 0; it < 2; ++it) {
            int tt = tid + it * 256;
            int bn = tt >> 2, bc = (tt & 3) * 8;
            int pos = nbrs[kk][bn];
            dst[it] = (pos >= 0) ? *(const half8*)(rh + (size_t)pos * 32 + bc) : zero8;
        }
    };

    gatherA(0, &pA);
    gatherB(0, pB);

    for (int kk = 0; kk < 9; ++kk) {
        __syncthreads();
        *(half8*)&Ah[ap * 40 + ac] = pA;
#pragma unroll
        for (int it = 0; it < 2; ++it) {
            int tt = tid + it * 256;
            int rrow = tt >> 2, rc = (tt & 3) * 8;
            *(half8*)&Bh[rrow * 40 + rc] = pB[it];
        }
        if (kk < 8) {
            gatherA(kk + 1, &pA);
            gatherB(kk + 1, pB);
        }
        __syncthreads();
        half8 af[4], bf[2];
#pragma unroll
        for (int m = 0; m < 4; ++m)
            af[m] = *(const half8*)&Ah[(m * 16 + row16) * 40 + quad * 8];
#pragma unroll
        for (int nb = 0; nb < 2; ++nb)
            bf[nb] = *(const half8*)&Bh[(wave * 32 + nb * 16 + row16) * 40 + quad * 8];
#pragma unroll
        for (int m = 0; m < 4; ++m)
#pragma unroll
            for (int nb = 0; nb < 2; ++nb)
                acc[m][nb] = __builtin_amdgcn_mfma_f32_16x16x32_f16(af[m], bf[nb], acc[m][nb], 0, 0, 0);
    }

    // ---- epilogue: v = acc*sinv[n]; t = exp(v - Mub[p]); per-wave LDS transpose -> 16B stores ----
    int nn[2];
    float sv[2];
    bool valid[2];
#pragma unroll
    for (int nb = 0; nb < 2; ++nb) {
        nn[nb] = n0 + wave * 32 + nb * 16 + row16;
        valid[nb] = nn[nb] < NTOT;
        sv[nb] = valid[nb] ? sinv[(size_t)(b0 + cb) * NTOT + nn[nb]] : 0.f;
    }
    float sm[4][4];
#pragma unroll
    for (int m = 0; m < 4; ++m)
#pragma unroll
        for (int r = 0; r < 4; ++r) sm[m][r] = 0.f;

    int tr = lane >> 2, tc = (lane & 3) * 8;   // transpose-read coords (wave-local)
#pragma unroll
    for (int m = 0; m < 4; ++m) {
#pragma unroll
        for (int nb = 0; nb < 2; ++nb) {
#pragma unroll
            for (int r = 0; r < 4; ++r) {
                float mub = sMub[m * 16 + quad * 4 + r];
                float e = valid[nb] ? __expf(acc[m][nb][r] * sv[nb] - mub) : 0.f;
                Tls[wave][(quad * 4 + r) * 40 + nb * 16 + row16] = (__bf16)e;
                sm[m][r] += e;
            }
        }
        // wave-local consume (no block barrier needed)
        bf16x8 v = *(const bf16x8*)&Tls[wave][tr * 40 + tc];
        *(bf16x8*)&tbuf[((size_t)cb * HW + p0 + m * 16 + tr) * NPAD2 + n0 + wave * 32 + tc] = v;
    }

#pragma unroll
    for (int msk = 1; msk < 16; msk <<= 1)
#pragma unroll
        for (int m = 0; m < 4; ++m)
#pragma unroll
            for (int r = 0; r < 4; ++r) sm[m][r] += __shfl_xor(sm[m][r], msk, 64);
    if (row16 == 0)
#pragma unroll
        for (int m = 0; m < 4; ++m)
#pragma unroll
            for (int r = 0; r < 4; ++r) redS[wave][m * 16 + quad * 4 + r] = sm[m][r];
    __syncthreads();
    if (wave == 0 && row16 == 0) {
#pragma unroll
        for (int m = 0; m < 4; ++m)
#pragma unroll
            for (int r = 0; r < 4; ++r) {
                int p = m * 16 + quad * 4 + r;
                float S = redS[0][p] + redS[1][p] + redS[2][p] + redS[3][p];
                partS[((size_t)cb * HW + p0 + p) * NT26 + ntile] = S;
            }
    }
}

// ---------------- row sum reduce ----------------
__global__ void k_rowsum(const float* __restrict__ partS, float* __restrict__ fin) {
    int row = blockIdx.x * 256 + threadIdx.x;
    float s = 0.f;
#pragma unroll
    for (int nt = 0; nt < NT26; ++nt) s += partS[(size_t)row * NT26 + nt];
    fin[row] = 1.0f / fmaxf(s, 1e-38f);
}

// ---------------- fold GEMM (MFMA bf16, 64m x 128p tile, K-step 32, low LDS for occupancy) ----------------
// grid x = ptile (8 consecutive blocks share Vb A-tile; tbuf streams) — do NOT swap (R12 lesson)
// FSTR 40 (80B rows): LDS 15.4 KB -> ~10 blocks/CU; cross-block overlap hides barrier drains (R14 lesson)
#define FSTR 40
__global__ void k_fold_mfma(const __bf16* __restrict__ Vb, const __bf16* __restrict__ tbuf,
                            const float* __restrict__ fin, float* __restrict__ outacc) {
    int ptile = blockIdx.x;   // 8 tiles of 128 p
    int mtile = blockIdx.y;   // 9 tiles of 64 m
    int cb    = blockIdx.z;
    int tid  = threadIdx.x;
    int lane = tid & 63, wave = tid >> 6;
    int row16 = lane & 15, quad = lane >> 4;

    __shared__ __bf16 Als[64 * FSTR];
    __shared__ __bf16 Bls[128 * FSTR];

    const __bf16* Vp = Vb   + (size_t)cb * 576 * NPAD2 + (size_t)mtile * 64 * NPAD2;
    const __bf16* Pp = tbuf + (size_t)cb * HW  * NPAD2 + (size_t)ptile * 128 * NPAD2;

    f32x4 acc[4][2];
#pragma unroll
    for (int i = 0; i < 4; ++i)
#pragma unroll
        for (int j = 0; j < 2; ++j) acc[i][j] = (f32x4){0.f, 0.f, 0.f, 0.f};

    // staging: 192 rows (64 A + 128 B) x 32 k = 768 16B-tasks / 256 thr = 3 each
    int srow = tid >> 2, soct = (tid & 3) * 8;   // task 0: rows 0..63 (A)
    bf16x8 pf[3];
    auto gather = [&](int k0) {
        pf[0] = *(const bf16x8*)(Vp + (size_t)srow * NPAD2 + k0 + soct);
#pragma unroll
        for (int i = 1; i < 3; ++i) {
            int t2 = tid + i * 256;
            int r2 = (t2 >> 2) - 64, o2 = (t2 & 3) * 8;
            pf[i] = *(const bf16x8*)(Pp + (size_t)r2 * NPAD2 + k0 + o2);
        }
    };

    gather(0);

    for (int k0 = 0; k0 < NPAD2; k0 += 32) {
        __syncthreads();
        *(bf16x8*)&Als[srow * FSTR + soct] = pf[0];
#pragma unroll
        for (int i = 1; i < 3; ++i) {
            int t2 = tid + i * 256;
            int r2 = (t2 >> 2) - 64, o2 = (t2 & 3) * 8;
            *(bf16x8*)&Bls[r2 * FSTR + o2] = pf[i];
        }
        if (k0 + 32 < NPAD2) gather(k0 + 32);
        __syncthreads();
        bf16x8 af[4], bf[2];
#pragma unroll
        for (int mb = 0; mb < 4; ++mb)
            af[mb] = *(const bf16x8*)&Als[(mb * 16 + row16) * FSTR + quad * 8];
#pragma unroll
        for (int pbi = 0; pbi < 2; ++pbi)
            bf[pbi] = *(const bf16x8*)&Bls[(wave * 32 + pbi * 16 + row16) * FSTR + quad * 8];
#pragma unroll
        for (int mb = 0; mb < 4; ++mb)
#pragma unroll
            for (int pbi = 0; pbi < 2; ++pbi)
                acc[mb][pbi] = __builtin_amdgcn_mfma_f32_16x16x32_bf16(af[mb], bf[pbi], acc[mb][pbi], 0, 0, 0);
    }
    float fsc[2];
#pragma unroll
    for (int pbi = 0; pbi < 2; ++pbi)
        fsc[pbi] = fin[(size_t)cb * HW + ptile * 128 + wave * 32 + pbi * 16 + row16];
#pragma unroll
    for (int mb = 0; mb < 4; ++mb)
#pragma unroll
        for (int pbi = 0; pbi < 2; ++pbi) {
#pragma unroll
            for (int r = 0; r < 4; ++r) {
                int mg = mtile * 64 + mb * 16 + quad * 4 + r;
                int pg = ptile * 128 + wave * 32 + pbi * 16 + row16;
                outacc[((size_t)cb * 576 + mg) * HW + pg] = acc[mb][pbi][r] * fsc[pbi];
            }
        }
}

// ---------------- epilogue ----------------
__global__ void k_epilogue(const float* __restrict__ x, const float* __restrict__ outacc,
                           float* __restrict__ out, int b0) {
    int t = blockIdx.x * blockDim.x + threadIdx.x;
    int cb = t >> 16;
    int c = (t >> 10) & 63;
    int p = t & 1023;
    int b = b0 + cb;
    int y = p >> 5, xx = p & 31;
    float acc = 0.f;
#pragma unroll
    for (int ky = 0; ky < 3; ++ky)
#pragma unroll
        for (int kx = 0; kx < 3; ++kx) {
            int py = y + 1 - ky, px = xx + 1 - kx;
            if (py >= 0 && py < HH && px >= 0 && px < WW)
                acc += outacc[((size_t)cb * 576 + c * 9 + ky * 3 + kx) * HW + py * WW + px];
        }
    size_t o = ((size_t)b * CC + c) * HW + p;
    out[o] = x[o] + 0.25f * acc;
}

extern "C" void kernel_launch(void* const* d_in, const int* in_sizes, int n_in,
                              void* d_out, int out_size, void* d_ws, size_t ws_size,
                              hipStream_t stream) {
    const float* x       = (const float*)d_in[0];
    const float* w_base  = (const float*)d_in[1];
    const float* b_base  = (const float*)d_in[2];
    const float* a_base  = (const float*)d_in[3];
    const float* w_match = (const float*)d_in[4];
    const float* b_match = (const float*)d_in[5];
    const float* a_match = (const float*)d_in[6];
    const float* w_asm   = (const float*)d_in[7];
    const float* b_asm   = (const float*)d_in[8];
    const float* a_asm   = (const float*)d_in[9];
    float* out = (float*)d_out;

    const size_t fixed = ((size_t)BB * HW * 32 * 2) * 2 + ((size_t)BB * CC * HW * 2) +
                         ((size_t)BB * HW * 4) * 3 + ((size_t)BB * NTOT * 4) +
                         ((size_t)9 * NTOT * 4) + 65536;
    const size_t perCB = ((size_t)HW * NPAD2 * 2) + ((size_t)HW * NT26 * 4) +
                         ((size_t)HW * 4) + ((size_t)576 * NPAD2 * 2) +
                         ((size_t)576 * HW * 4) + 65536;
    int CB = 32;
    while (CB > 1 && fixed + perCB * CB > ws_size) CB >>= 1;

    char* ws = (char*)d_ws;
    size_t off = 0;
    auto alloc_b = [&](size_t bytes) {
        void* p = (void*)(ws + off);
        off += bytes;
        off = (off + 255) & ~(size_t)255;
        return p;
    };
    _Float16* mft   = (_Float16*)alloc_b((size_t)BB * HW * 32 * 2);
    _Float16* rft   = (_Float16*)alloc_b((size_t)BB * HW * 32 * 2);
    __bf16* base_f  = (__bf16*)alloc_b((size_t)BB * CC * HW * 2);
    float*  mbss    = (float*)alloc_b((size_t)BB * HW * 4);
    float*  rmss    = (float*)alloc_b((size_t)BB * HW * 4);
    float*  qub     = (float*)alloc_b((size_t)BB * HW * 4);
    float*  sinv    = (float*)alloc_b((size_t)BB * NTOT * 4);
    int*    nbr_pos = (int*)alloc_b((size_t)9 * NTOT * 4);
    __bf16* tbuf    = (__bf16*)alloc_b((size_t)CB * HW * NPAD2 * 2);
    float*  partS   = (float*)alloc_b((size_t)CB * HW * NT26 * 4);
    float*  fin     = (float*)alloc_b((size_t)CB * HW * 4);
    __bf16* Vb      = (__bf16*)alloc_b((size_t)CB * 576 * NPAD2 * 2);
    float*  outacc  = (float*)alloc_b((size_t)CB * 576 * HW * 4);
    if (off > ws_size) return;

    k_feats<<<BB * HW / 64, 256, 0, stream>>>(
        x, w_base, b_base, a_base, w_match, b_match, a_match, w_asm, b_asm, a_asm,
        mft, rft, base_f, mbss, rmss);
    k_nbr<<<(NTOT + 255) / 256, 256, 0, stream>>>(nbr_pos);
    k_qnorm<<<BB * HW / 256, 256, 0, stream>>>(mbss, qub);
    k_norms<<<(BB * NTOT + 255) / 256, 256, 0, stream>>>(rmss, nbr_pos, sinv);

    for (int b0 = 0; b0 < BB; b0 += CB) {
        k_corr_mfma<<<dim3(16, NT26, CB), 256, 0, stream>>>(
            mft, rft, nbr_pos, sinv, qub, tbuf, partS, b0);
        k_rowsum<<<CB * HW / 256, 256, 0, stream>>>(partS, fin);
        k_vgather<<<dim3(576 * (NPAD2 / 8) / 256, CB), 256, 0, stream>>>(base_f, nbr_pos, Vb, b0);
        k_fold_mfma<<<dim3(8, 9, CB), 256, 0, stream>>>(Vb, tbuf, fin, outacc);
        k_epilogue<<<CB * CC * HW / 256, 256, 0, stream>>>(x, outacc, out, b0);
    }
}

// Round 17
// 650.224 us; speedup vs baseline: 1.0760x; 1.0760x over previous
//
#include <hip/hip_runtime.h>
#include <hip/hip_bf16.h>
#include <math.h>

#define BB 32
#define CC 64
#define C2 32
#define HH 32
#define WW 32
#define HW 1024
#define NTOT 3278
#define NPAD2 3328   // padded N (multiple of 128) for MFMA corr + fold
#define NT26 26      // NPAD2 / 128

typedef __bf16   bf16x8 __attribute__((ext_vector_type(8)));
typedef _Float16 half8  __attribute__((ext_vector_type(8)));
typedef float    f32x4  __attribute__((ext_vector_type(4)));

__device__ __constant__ int SC_SIZE[5] = {32, 28, 25, 22, 19};
__device__ __constant__ int SC_OFF[6]  = {0, 1024, 1808, 2433, 2917, 3278};

// ---------------- fused feature kernel: LDS-staged, x read once ----------------
#define XS_STR 65
#define WS_STR 132
__global__ void __launch_bounds__(256, 1) k_feats(
        const float* __restrict__ x,
        const float* __restrict__ wb, const float* __restrict__ bb, const float* __restrict__ ab,
        const float* __restrict__ wm, const float* __restrict__ bm, const float* __restrict__ am,
        const float* __restrict__ wa, const float* __restrict__ ba, const float* __restrict__ aa,
        _Float16* __restrict__ mft, _Float16* __restrict__ rft,
        __bf16* __restrict__ basef,
        float* __restrict__ mbss, float* __restrict__ rmss) {
    __shared__ float Xs[64 * XS_STR];     // [c][p]
    __shared__ float Wls[64 * WS_STR];    // [c][o]
    __shared__ float bsh[128];
    __shared__ float ash3[3];
    int tid = threadIdx.x;
    int g0 = blockIdx.x * 64;
    int b = g0 >> 10, p0 = g0 & 1023;

    const float* xb = x + (size_t)b * CC * HW + p0;
    for (int i = tid; i < 64 * 64; i += 256) {
        int c = i >> 6, p = i & 63;
        Xs[c * XS_STR + p] = xb[(size_t)c * HW + p];
    }
    for (int i = tid; i < 128 * 64; i += 256) {
        int o = i >> 6, c = i & 63;
        float w = (o < 32) ? wb[o * CC + c] : (o < 64) ? wm[(o - 32) * CC + c] : wa[(o - 64) * CC + c];
        Wls[c * WS_STR + o] = w;
    }
    if (tid < 128) bsh[tid] = (tid < 32) ? bb[tid] : (tid < 64) ? bm[tid - 32] : ba[tid - 64];
    if (tid == 128) ash3[0] = ab[0];
    if (tid == 129) ash3[1] = am[0];
    if (tid == 130) ash3[2] = aa[0];
    __syncthreads();

    int p = tid & 63, og = tid >> 6;
    int o0 = og * 32;
    float acc[32];
#pragma unroll
    for (int oi = 0; oi < 32; ++oi) acc[oi] = bsh[o0 + oi];
    for (int c = 0; c < 64; ++c) {
        float xv = Xs[c * XS_STR + p];
        const float* wr = &Wls[c * WS_STR + o0];
#pragma unroll
        for (int oi = 0; oi < 32; ++oi) acc[oi] += wr[oi] * xv;
    }
    int pp = p0 + p;
    if (og < 2) {
        float alpha = ash3[og], ss = 0.f;
        half8 hv[4];
#pragma unroll
        for (int oi = 0; oi < 32; ++oi) {
            float v = acc[oi] >= 0.f ? acc[oi] : alpha * acc[oi];
            ss += v * v;
            hv[oi >> 3][oi & 7] = (_Float16)v;
        }
        _Float16* d = (og == 0 ? mft : rft) + ((size_t)b * HW + pp) * 32;
#pragma unroll
        for (int q = 0; q < 4; ++q) *(half8*)&d[q * 8] = hv[q];
        if (og == 0) mbss[(size_t)b * HW + pp] = ss;
        else         rmss[(size_t)b * HW + pp] = ss;
    } else {
        float alpha = ash3[2];
        int ob = o0 - 64;
#pragma unroll
        for (int oi = 0; oi < 32; ++oi) {
            float v = acc[oi] >= 0.f ? acc[oi] : alpha * acc[oi];
            basef[((size_t)b * CC + ob + oi) * HW + pp] = (__bf16)v;
        }
    }
}

// ---------------- neighbor table ----------------
__global__ void k_nbr(int* __restrict__ nbr_pos) {
    int n = blockIdx.x * blockDim.x + threadIdx.x;
    if (n >= NTOT) return;
    int s = 0;
    while (s < 4 && n >= SC_OFF[s + 1]) ++s;
    int q = n - SC_OFF[s];
    int hs = SC_SIZE[s];
    int ny = q / hs, nx = q % hs;
    for (int dy = 0; dy < 3; ++dy)
        for (int dx = 0; dx < 3; ++dx) {
            int yy = ny + dy - 1, xx = nx + dx - 1;
            int pos = -1;
            if (yy >= 0 && yy < hs && xx >= 0 && xx < hs)
                pos = ((yy * HH) / hs) * WW + (xx * WW) / hs;
            nbr_pos[(dy * 3 + dx) * NTOT + n] = pos;
        }
}

// ---------------- per-(b,p) logit upper bound ----------------
__global__ void k_qnorm(const float* __restrict__ mbss, float* __restrict__ qub) {
    int t = blockIdx.x * blockDim.x + threadIdx.x;
    int b = t >> 10, p = t & 1023;
    int y = p >> 5, x = p & 31;
    float s = 0.f;
#pragma unroll
    for (int dy = 0; dy < 3; ++dy)
#pragma unroll
        for (int dx = 0; dx < 3; ++dx) {
            int yy = y + dy - 1, xx = x + dx - 1;
            if (yy >= 0 && yy < HH && xx >= 0 && xx < WW)
                s += mbss[(size_t)b * HW + yy * WW + xx];
        }
    qub[t] = 10.0f * sqrtf(s);
}

// ---------------- per-(b,n) filter norms ----------------
__global__ void k_norms(const float* __restrict__ rmss, const int* __restrict__ nbr_pos,
                        float* __restrict__ sinv) {
    int t = blockIdx.x * blockDim.x + threadIdx.x;
    if (t >= BB * NTOT) return;
    int b = t / NTOT, n = t % NTOT;
    float sum = 0.f;
#pragma unroll
    for (int kk = 0; kk < 9; ++kk) {
        int pos = nbr_pos[kk * NTOT + n];
        if (pos >= 0) sum += rmss[(size_t)b * HW + pos];
    }
    sinv[t] = 10.0f / fmaxf(sqrtf(sum), 1e-4f);
}

// ---------------- V gather (vectorized): thread -> 8 consecutive n ----------------
__global__ void k_vgather(const __bf16* __restrict__ basef, const int* __restrict__ nbr_pos,
                          __bf16* __restrict__ Vb, int b0) {
    int t = blockIdx.x * 256 + threadIdx.x;
    int cb = blockIdx.y;
    int m = t / (NPAD2 / 8), nq = t % (NPAD2 / 8);
    int c = m / 9, kk = m - c * 9;
    const __bf16* bfp = basef + ((size_t)(b0 + cb) * CC + c) * HW;
    const int* nb = &nbr_pos[kk * NTOT];
    int n0 = nq * 8;
    bf16x8 v8;
#pragma unroll
    for (int u = 0; u < 8; ++u) {
        int n = n0 + u;
        __bf16 v = (__bf16)0.f;
        if (n < NTOT) {
            int pos = nb[n];
            if (pos >= 0) v = bfp[pos];
        }
        v8[u] = v;
    }
    *(bf16x8*)&Vb[((size_t)cb * 576 + m) * NPAD2 + n0] = v8;
}

// ---------------- correlation GEMM: fp16, 64x128 tile, reg prefetch, wave-local store ----------------
__global__ void k_corr_mfma(const _Float16* __restrict__ mft, const _Float16* __restrict__ rft,
                            const int* __restrict__ nbr_pos,
                            const float* __restrict__ sinv, const float* __restrict__ qub,
                            __bf16* __restrict__ tbuf, float* __restrict__ partS, int b0) {
    int ptile = blockIdx.x;   // 16 tiles of 64 p
    int ntile = blockIdx.y;   // 26 tiles of 128 n
    int cb    = blockIdx.z;
    int tid  = threadIdx.x;
    int lane = tid & 63, wave = tid >> 6;
    int row16 = lane & 15, quad = lane >> 4;
    int p0 = ptile * 64, n0 = ntile * 128;

    __shared__ _Float16 Ah[64 * 40];
    __shared__ _Float16 Bh[128 * 40];
    __shared__ int   nbrs[9][128];
    __shared__ float sMub[64];
    __shared__ float redS[4][64];
    __shared__ __bf16 Tls[4][16 * 40];   // per-wave transpose slab (16 rows x 32 cols)

    if (tid < 64) sMub[tid] = qub[(size_t)(b0 + cb) * HW + p0 + tid];
    for (int i = tid; i < 9 * 128; i += 256) {
        int kk = i >> 7, j = i & 127;
        int n = n0 + j;
        nbrs[kk][j] = (n < NTOT) ? nbr_pos[kk * NTOT + n] : -1;
    }

    const _Float16* mh = mft + (size_t)(b0 + cb) * HW * 32;
    const _Float16* rh = rft + (size_t)(b0 + cb) * HW * 32;

    f32x4 acc[4][2];
#pragma unroll
    for (int i = 0; i < 4; ++i)
#pragma unroll
        for (int j = 0; j < 2; ++j) acc[i][j] = (f32x4){0.f, 0.f, 0.f, 0.f};

    half8 zero8;
#pragma unroll
    for (int u = 0; u < 8; ++u) zero8[u] = (_Float16)0.f;

    __syncthreads();   // nbrs, sMub ready

    half8 pA, pB[2];
    int ap = tid >> 2, ac = (tid & 3) * 8;   // A task: 64 p x 4 c-octs = 256 tasks
    int pg = p0 + ap, ay = pg >> 5, ax = pg & 31;
    auto gatherA = [&](int kk, half8* dst) {
        int py = ay + kk / 3 - 1, px = ax + (kk % 3) - 1;
        bool ok = (py >= 0 && py < HH && px >= 0 && px < WW);
        *dst = ok ? *(const half8*)(mh + (size_t)(py * WW + px) * 32 + ac) : zero8;
    };
    auto gatherB = [&](int kk, half8* dst) {
#pragma unroll
        for (int it = 0; it < 2; ++it) {
            int tt = tid + it * 256;
            int bn = tt >> 2, bc = (tt & 3) * 8;
            int pos = nbrs[kk][bn];
            dst[it] = (pos >= 0) ? *(const half8*)(rh + (size_t)pos * 32 + bc) : zero8;
        }
    };

    gatherA(0, &pA);
    gatherB(0, pB);

    for (int kk = 0; kk < 9; ++kk) {
        __syncthreads();
        *(half8*)&Ah[ap * 40 + ac] = pA;
#pragma unroll
        for (int it = 0; it < 2; ++it) {
            int tt = tid + it * 256;
            int rrow = tt >> 2, rc = (tt & 3) * 8;
            *(half8*)&Bh[rrow * 40 + rc] = pB[it];
        }
        if (kk < 8) {
            gatherA(kk + 1, &pA);
            gatherB(kk + 1, pB);
        }
        __syncthreads();
        half8 af[4], bf[2];
#pragma unroll
        for (int m = 0; m < 4; ++m)
            af[m] = *(const half8*)&Ah[(m * 16 + row16) * 40 + quad * 8];
#pragma unroll
        for (int nb = 0; nb < 2; ++nb)
            bf[nb] = *(const half8*)&Bh[(wave * 32 + nb * 16 + row16) * 40 + quad * 8];
#pragma unroll
        for (int m = 0; m < 4; ++m)
#pragma unroll
            for (int nb = 0; nb < 2; ++nb)
                acc[m][nb] = __builtin_amdgcn_mfma_f32_16x16x32_f16(af[m], bf[nb], acc[m][nb], 0, 0, 0);
    }

    // ---- epilogue: v = acc*sinv[n]; t = exp(v - Mub[p]); per-wave LDS transpose -> 16B stores ----
    int nn[2];
    float sv[2];
    bool valid[2];
#pragma unroll
    for (int nb = 0; nb < 2; ++nb) {
        nn[nb] = n0 + wave * 32 + nb * 16 + row16;
        valid[nb] = nn[nb] < NTOT;
        sv[nb] = valid[nb] ? sinv[(size_t)(b0 + cb) * NTOT + nn[nb]] : 0.f;
    }
    float sm[4][4];
#pragma unroll
    for (int m = 0; m < 4; ++m)
#pragma unroll
        for (int r = 0; r < 4; ++r) sm[m][r] = 0.f;

    int tr = lane >> 2, tc = (lane & 3) * 8;   // transpose-read coords (wave-local)
#pragma unroll
    for (int m = 0; m < 4; ++m) {
#pragma unroll
        for (int nb = 0; nb < 2; ++nb) {
#pragma unroll
            for (int r = 0; r < 4; ++r) {
                float mub = sMub[m * 16 + quad * 4 + r];
                float e = valid[nb] ? __expf(acc[m][nb][r] * sv[nb] - mub) : 0.f;
                Tls[wave][(quad * 4 + r) * 40 + nb * 16 + row16] = (__bf16)e;
                sm[m][r] += e;
            }
        }
        // wave-local consume (no block barrier needed)
        bf16x8 v = *(const bf16x8*)&Tls[wave][tr * 40 + tc];
        *(bf16x8*)&tbuf[((size_t)cb * HW + p0 + m * 16 + tr) * NPAD2 + n0 + wave * 32 + tc] = v;
    }

#pragma unroll
    for (int msk = 1; msk < 16; msk <<= 1)
#pragma unroll
        for (int m = 0; m < 4; ++m)
#pragma unroll
            for (int r = 0; r < 4; ++r) sm[m][r] += __shfl_xor(sm[m][r], msk, 64);
    if (row16 == 0)
#pragma unroll
        for (int m = 0; m < 4; ++m)
#pragma unroll
            for (int r = 0; r < 4; ++r) redS[wave][m * 16 + quad * 4 + r] = sm[m][r];
    __syncthreads();
    if (wave == 0 && row16 == 0) {
#pragma unroll
        for (int m = 0; m < 4; ++m)
#pragma unroll
            for (int r = 0; r < 4; ++r) {
                int p = m * 16 + quad * 4 + r;
                float S = redS[0][p] + redS[1][p] + redS[2][p] + redS[3][p];
                partS[((size_t)cb * HW + p0 + p) * NT26 + ntile] = S;
            }
    }
}

// ---------------- row sum reduce ----------------
__global__ void k_rowsum(const float* __restrict__ partS, float* __restrict__ fin) {
    int row = blockIdx.x * 256 + threadIdx.x;
    float s = 0.f;
#pragma unroll
    for (int nt = 0; nt < NT26; ++nt) s += partS[(size_t)row * NT26 + nt];
    fin[row] = 1.0f / fmaxf(s, 1e-38f);
}

// ---------------- fold GEMM (MFMA bf16, 64m x 128p, K-step 64, reg prefetch) — R14 config ----------------
// grid x = ptile (8 consecutive blocks share Vb A-tile; tbuf streams) — do NOT swap (R12 lesson)
// K64/FSTR72 is the measured local optimum (R15: 128m worse; R16: K32 worse)
#define FSTR 72   // LDS row stride in bf16 (144 B, 16B-aligned)
__global__ void k_fold_mfma(const __bf16* __restrict__ Vb, const __bf16* __restrict__ tbuf,
                            const float* __restrict__ fin, __bf16* __restrict__ outacc) {
    int ptile = blockIdx.x;   // 8 tiles of 128 p
    int mtile = blockIdx.y;   // 9 tiles of 64 m
    int cb    = blockIdx.z;
    int tid  = threadIdx.x;
    int lane = tid & 63, wave = tid >> 6;
    int row16 = lane & 15, quad = lane >> 4;

    __shared__ __bf16 Als[64 * FSTR];
    __shared__ __bf16 Bls[128 * FSTR];

    const __bf16* Vp = Vb   + (size_t)cb * 576 * NPAD2 + (size_t)mtile * 64 * NPAD2;
    const __bf16* Pp = tbuf + (size_t)cb * HW  * NPAD2 + (size_t)ptile * 128 * NPAD2;

    f32x4 acc[4][2];
#pragma unroll
    for (int i = 0; i < 4; ++i)
#pragma unroll
        for (int j = 0; j < 2; ++j) acc[i][j] = (f32x4){0.f, 0.f, 0.f, 0.f};

    int sr = tid >> 3, sk = (tid & 7) * 8;
    bf16x8 pa[2], pb[4];
#pragma unroll
    for (int i = 0; i < 2; ++i)
        pa[i] = *(const bf16x8*)(Vp + (size_t)(i * 32 + sr) * NPAD2 + sk);
#pragma unroll
    for (int i = 0; i < 4; ++i)
        pb[i] = *(const bf16x8*)(Pp + (size_t)(i * 32 + sr) * NPAD2 + sk);

    for (int k0 = 0; k0 < NPAD2; k0 += 64) {
        __syncthreads();
#pragma unroll
        for (int i = 0; i < 2; ++i)
            *(bf16x8*)&Als[(i * 32 + sr) * FSTR + sk] = pa[i];
#pragma unroll
        for (int i = 0; i < 4; ++i)
            *(bf16x8*)&Bls[(i * 32 + sr) * FSTR + sk] = pb[i];
        if (k0 + 64 < NPAD2) {
#pragma unroll
            for (int i = 0; i < 2; ++i)
                pa[i] = *(const bf16x8*)(Vp + (size_t)(i * 32 + sr) * NPAD2 + k0 + 64 + sk);
#pragma unroll
            for (int i = 0; i < 4; ++i)
                pb[i] = *(const bf16x8*)(Pp + (size_t)(i * 32 + sr) * NPAD2 + k0 + 64 + sk);
        }
        __syncthreads();
#pragma unroll
        for (int kh = 0; kh < 2; ++kh) {
            bf16x8 af[4], bf[2];
#pragma unroll
            for (int mb = 0; mb < 4; ++mb)
                af[mb] = *(const bf16x8*)&Als[(mb * 16 + row16) * FSTR + kh * 32 + quad * 8];
#pragma unroll
            for (int pbi = 0; pbi < 2; ++pbi)
                bf[pbi] = *(const bf16x8*)&Bls[(wave * 32 + pbi * 16 + row16) * FSTR + kh * 32 + quad * 8];
#pragma unroll
            for (int mb = 0; mb < 4; ++mb)
#pragma unroll
                for (int pbi = 0; pbi < 2; ++pbi)
                    acc[mb][pbi] = __builtin_amdgcn_mfma_f32_16x16x32_bf16(af[mb], bf[pbi], acc[mb][pbi], 0, 0, 0);
        }
    }
    float fsc[2];
#pragma unroll
    for (int pbi = 0; pbi < 2; ++pbi)
        fsc[pbi] = fin[(size_t)cb * HW + ptile * 128 + wave * 32 + pbi * 16 + row16];
#pragma unroll
    for (int mb = 0; mb < 4; ++mb)
#pragma unroll
        for (int pbi = 0; pbi < 2; ++pbi) {
#pragma unroll
            for (int r = 0; r < 4; ++r) {
                int mg = mtile * 64 + mb * 16 + quad * 4 + r;
                int pg = ptile * 128 + wave * 32 + pbi * 16 + row16;
                outacc[((size_t)cb * 576 + mg) * HW + pg] = (__bf16)(acc[mb][pbi][r] * fsc[pbi]);
            }
        }
}

// ---------------- epilogue (bf16 outacc) ----------------
__global__ void k_epilogue(const float* __restrict__ x, const __bf16* __restrict__ outacc,
                           float* __restrict__ out, int b0) {
    int t = blockIdx.x * blockDim.x + threadIdx.x;
    int cb = t >> 16;
    int c = (t >> 10) & 63;
    int p = t & 1023;
    int b = b0 + cb;
    int y = p >> 5, xx = p & 31;
    float acc = 0.f;
#pragma unroll
    for (int ky = 0; ky < 3; ++ky)
#pragma unroll
        for (int kx = 0; kx < 3; ++kx) {
            int py = y + 1 - ky, px = xx + 1 - kx;
            if (py >= 0 && py < HH && px >= 0 && px < WW)
                acc += (float)outacc[((size_t)cb * 576 + c * 9 + ky * 3 + kx) * HW + py * WW + px];
        }
    size_t o = ((size_t)b * CC + c) * HW + p;
    out[o] = x[o] + 0.25f * acc;
}

extern "C" void kernel_launch(void* const* d_in, const int* in_sizes, int n_in,
                              void* d_out, int out_size, void* d_ws, size_t ws_size,
                              hipStream_t stream) {
    const float* x       = (const float*)d_in[0];
    const float* w_base  = (const float*)d_in[1];
    const float* b_base  = (const float*)d_in[2];
    const float* a_base  = (const float*)d_in[3];
    const float* w_match = (const float*)d_in[4];
    const float* b_match = (const float*)d_in[5];
    const float* a_match = (const float*)d_in[6];
    const float* w_asm   = (const float*)d_in[7];
    const float* b_asm   = (const float*)d_in[8];
    const float* a_asm   = (const float*)d_in[9];
    float* out = (float*)d_out;

    const size_t fixed = ((size_t)BB * HW * 32 * 2) * 2 + ((size_t)BB * CC * HW * 2) +
                         ((size_t)BB * HW * 4) * 3 + ((size_t)BB * NTOT * 4) +
                         ((size_t)9 * NTOT * 4) + 65536;
    const size_t perCB = ((size_t)HW * NPAD2 * 2) + ((size_t)HW * NT26 * 4) +
                         ((size_t)HW * 4) + ((size_t)576 * NPAD2 * 2) +
                         ((size_t)576 * HW * 2) + 65536;
    int CB = 32;
    while (CB > 1 && fixed + perCB * CB > ws_size) CB >>= 1;

    char* ws = (char*)d_ws;
    size_t off = 0;
    auto alloc_b = [&](size_t bytes) {
        void* p = (void*)(ws + off);
        off += bytes;
        off = (off + 255) & ~(size_t)255;
        return p;
    };
    _Float16* mft   = (_Float16*)alloc_b((size_t)BB * HW * 32 * 2);
    _Float16* rft   = (_Float16*)alloc_b((size_t)BB * HW * 32 * 2);
    __bf16* base_f  = (__bf16*)alloc_b((size_t)BB * CC * HW * 2);
    float*  mbss    = (float*)alloc_b((size_t)BB * HW * 4);
    float*  rmss    = (float*)alloc_b((size_t)BB * HW * 4);
    float*  qub     = (float*)alloc_b((size_t)BB * HW * 4);
    float*  sinv    = (float*)alloc_b((size_t)BB * NTOT * 4);
    int*    nbr_pos = (int*)alloc_b((size_t)9 * NTOT * 4);
    __bf16* tbuf    = (__bf16*)alloc_b((size_t)CB * HW * NPAD2 * 2);
    float*  partS   = (float*)alloc_b((size_t)CB * HW * NT26 * 4);
    float*  fin     = (float*)alloc_b((size_t)CB * HW * 4);
    __bf16* Vb      = (__bf16*)alloc_b((size_t)CB * 576 * NPAD2 * 2);
    __bf16* outacc  = (__bf16*)alloc_b((size_t)CB * 576 * HW * 2);
    if (off > ws_size) return;

    k_feats<<<BB * HW / 64, 256, 0, stream>>>(
        x, w_base, b_base, a_base, w_match, b_match, a_match, w_asm, b_asm, a_asm,
        mft, rft, base_f, mbss, rmss);
    k_nbr<<<(NTOT + 255) / 256, 256, 0, stream>>>(nbr_pos);
    k_qnorm<<<BB * HW / 256, 256, 0, stream>>>(mbss, qub);
    k_norms<<<(BB * NTOT + 255) / 256, 256, 0, stream>>>(rmss, nbr_pos, sinv);

    for (int b0 = 0; b0 < BB; b0 += CB) {
        k_corr_mfma<<<dim3(16, NT26, CB), 256, 0, stream>>>(
            mft, rft, nbr_pos, sinv, qub, tbuf, partS, b0);
        k_rowsum<<<CB * HW / 256, 256, 0, stream>>>(partS, fin);
        k_vgather<<<dim3(576 * (NPAD2 / 8) / 256, CB), 256, 0, stream>>>(base_f, nbr_pos, Vb, b0);
        k_fold_mfma<<<dim3(8, 9, CB), 256, 0, stream>>>(Vb, tbuf, fin, outacc);
        k_epilogue<<<CB * CC * HW / 256, 256, 0, stream>>>(x, outacc, out, b0);
    }
}